// Round 3
// baseline (221.506 us; speedup 1.0000x reference)
//
#include <hip/hip_runtime.h>

#define NB   64
#define NOBJ 50
#define ND   8732
#define BLK  1024
#define CHUNK 10
#define NCHUNK 5
#define NWAVE (BLK/64)

// cross-kernel per-batch partials: npos, sum_l1, sum_ce_pos, k(num_neg), sum_topk
__device__ float g_part[NB * 5];

__global__ __launch_bounds__(BLK) void mbl_main(const float* __restrict__ loc_data,
                                                const float* __restrict__ conf_data,
                                                const float* __restrict__ dbox,
                                                const float* __restrict__ targets) {
    __shared__ float s_tx1[NOBJ], s_ty1[NOBJ], s_tx2[NOBJ], s_ty2[NOBJ], s_area[NOBJ], s_lab[NOBJ];
    __shared__ float s_val[ND];            // phase1: best_truth_overlap; phase2+: ce_mined
    __shared__ unsigned short s_bti[ND];   // best_truth_idx (phase2 adds pos flag in bit 15)
    __shared__ unsigned long long s_key[NOBJ];
    __shared__ unsigned long long s_wkey[NWAVE][CHUNK];
    __shared__ float s_redf[NWAVE], s_redf2[NWAVE], s_redf3[NWAVE];
    __shared__ int   s_redi[NWAVE];
    __shared__ int   s_cnt_bc;
    __shared__ int   s_k;

    const int b    = blockIdx.x;
    const int tid  = threadIdx.x;
    const int lane = tid & 63;
    const int wv   = tid >> 6;

    // ---- load truths ----
    if (tid < NOBJ) {
        const float* t = targets + (b * NOBJ + tid) * 5;
        float x1 = t[0], y1 = t[1], x2 = t[2], y2 = t[3], lb = t[4];
        s_tx1[tid] = x1; s_ty1[tid] = y1; s_tx2[tid] = x2; s_ty2[tid] = y2;
        s_area[tid] = (x2 - x1) * (y2 - y1);
        s_lab[tid] = lb;
    }
    __syncthreads();

    // ---- phase 1: IoU, per-prior best truth (first-max), per-truth best prior ----
    for (int c = 0; c < NCHUNK; ++c) {
        float ttx1[CHUNK], tty1[CHUNK], ttx2[CHUNK], tty2[CHUNK], tta[CHUNK];
#pragma unroll
        for (int jj = 0; jj < CHUNK; ++jj) {
            int j = c * CHUNK + jj;
            ttx1[jj] = s_tx1[j]; tty1[jj] = s_ty1[j];
            ttx2[jj] = s_tx2[j]; tty2[jj] = s_ty2[j];
            tta[jj]  = s_area[j];
        }
        unsigned long long key[CHUNK];
#pragma unroll
        for (int jj = 0; jj < CHUNK; ++jj) key[jj] = 0ull;

        for (int d = tid; d < ND; d += BLK) {
            const float* p = dbox + d * 4;
            float cx = p[0], cy = p[1], w = p[2], h = p[3];
            float px1 = cx - 0.5f * w, py1 = cy - 0.5f * h;
            float px2 = cx + 0.5f * w, py2 = cy + 0.5f * h;
            float pa = (px2 - px1) * (py2 - py1);
            float bov; int bj;
            if (c == 0) { bov = -1.0f; bj = 0; }
            else        { bov = s_val[d]; bj = (int)s_bti[d]; }
#pragma unroll
            for (int jj = 0; jj < CHUNK; ++jj) {
                float ltx = fmaxf(ttx1[jj], px1), lty = fmaxf(tty1[jj], py1);
                float rbx = fminf(ttx2[jj], px2), rby = fminf(tty2[jj], py2);
                float ww = fmaxf(rbx - ltx, 0.0f), hh = fmaxf(rby - lty, 0.0f);
                float inter = ww * hh;
                float iou = inter / (tta[jj] + pa - inter);
                if (iou > bov) { bov = iou; bj = c * CHUNK + jj; }
                unsigned long long enc =
                    ((unsigned long long)__float_as_uint(iou) << 32) |
                    (unsigned long long)(0xFFFFFFFFu - (unsigned)d);
                if (enc > key[jj]) key[jj] = enc;
            }
            s_val[d] = bov;
            s_bti[d] = (unsigned short)bj;
        }
        // reduce per-truth keys: wave butterfly, then across waves
#pragma unroll
        for (int jj = 0; jj < CHUNK; ++jj) {
            unsigned long long k0 = key[jj];
            for (int off = 32; off >= 1; off >>= 1) {
                unsigned long long o = __shfl_xor(k0, off, 64);
                if (o > k0) k0 = o;
            }
            if (lane == 0) s_wkey[wv][jj] = k0;
        }
        __syncthreads();
        if (tid < CHUNK) {
            unsigned long long k0 = s_wkey[0][tid];
            for (int wq = 1; wq < NWAVE; ++wq) {
                unsigned long long o = s_wkey[wq][tid];
                if (o > k0) k0 = o;
            }
            s_key[c * CHUNK + tid] = k0;
        }
        __syncthreads();
    }

    // ---- sequential scatter (last-write-wins, matches .at[].set semantics) ----
    if (tid == 0) {
#pragma unroll 1
        for (int j = 0; j < NOBJ; ++j) {
            unsigned int d = 0xFFFFFFFFu - (unsigned int)(s_key[j] & 0xFFFFFFFFull);
            s_val[d] = 2.0f;
            s_bti[d] = (unsigned short)j;
        }
    }
    __syncthreads();

    // ---- phase 2: encode + smooth-L1 + CE; write ce_mined into s_val ----
    float npos = 0.0f, sl1 = 0.0f, scep = 0.0f;
    for (int d = tid; d < ND; d += BLK) {
        float ov = s_val[d];
        int j = (int)s_bti[d];
        bool pos = !(ov < 0.5f);
        const float* cf = conf_data + ((size_t)b * ND + d) * 2;
        float x0 = cf[0], x1 = cf[1];
        float m = fmaxf(x0, x1);
        float lse = m + logf(expf(x0 - m) + expf(x1 - m));
        int lab = pos ? ((int)s_lab[j] + 1) : 0;
        float ce = lse - (lab >= 1 ? x1 : x0);
        s_val[d] = pos ? 0.0f : ce;
        s_bti[d] = (unsigned short)(j | (pos ? 0x8000 : 0));
        if (pos) {
            npos += 1.0f;
            scep += ce;
            const float* p = dbox + d * 4;
            float cx = p[0], cy = p[1], w = p[2], h = p[3];
            float tx1 = s_tx1[j], ty1 = s_ty1[j], tx2 = s_tx2[j], ty2 = s_ty2[j];
            float g0 = ((tx1 + tx2) * 0.5f - cx) / (0.1f * w);
            float g1 = ((ty1 + ty2) * 0.5f - cy) / (0.1f * h);
            float g2 = logf((tx2 - tx1) / w) / 0.2f;
            float g3 = logf((ty2 - ty1) / h) / 0.2f;
            const float* ld = loc_data + ((size_t)b * ND + d) * 4;
            float tt[4] = {g0, g1, g2, g3};
#pragma unroll
            for (int q = 0; q < 4; ++q) {
                float dd = fabsf(ld[q] - tt[q]);
                sl1 += (dd < 1.0f) ? 0.5f * dd * dd : dd - 0.5f;
            }
        }
    }
    // block-reduce npos, sl1, scep
    for (int off = 32; off >= 1; off >>= 1) {
        npos += __shfl_xor(npos, off, 64);
        sl1  += __shfl_xor(sl1,  off, 64);
        scep += __shfl_xor(scep, off, 64);
    }
    if (lane == 0) { s_redf[wv] = npos; s_redf2[wv] = sl1; s_redf3[wv] = scep; }
    __syncthreads();
    if (tid == 0) {
        float a = 0.0f, bb = 0.0f, cc = 0.0f;
        for (int w2 = 0; w2 < NWAVE; ++w2) { a += s_redf[w2]; bb += s_redf2[w2]; cc += s_redf3[w2]; }
        int np = (int)a;
        int k = np * 3;
        if (k < 20) k = 20;
        if (k > ND) k = ND;
        s_k = k;
        g_part[b * 5 + 0] = a;
        g_part[b * 5 + 1] = bb;
        g_part[b * 5 + 2] = cc;
        g_part[b * 5 + 3] = (float)k;
    }
    __syncthreads();
    const int k = s_k;

    // ---- phase 3: k-th largest of ce_mined via binary search on bit pattern ----
    unsigned int lo = 0u, hi = 0x7f7fffffu;
    while (lo < hi) {
        unsigned int mid = lo + ((hi - lo + 1u) >> 1);
        int cnt = 0;
        for (int d = tid; d < ND; d += BLK)
            cnt += (__float_as_uint(s_val[d]) >= mid) ? 1 : 0;
        for (int off = 32; off >= 1; off >>= 1) cnt += __shfl_xor(cnt, off, 64);
        if (lane == 0) s_redi[wv] = cnt;
        __syncthreads();
        if (tid == 0) {
            int t = 0;
            for (int w2 = 0; w2 < NWAVE; ++w2) t += s_redi[w2];
            s_cnt_bc = t;
        }
        __syncthreads();
        int total = s_cnt_bc;
        if (total >= k) lo = mid; else hi = mid - 1u;
        __syncthreads();
    }
    float T = __uint_as_float(lo);

    int cgt = 0; float sgt = 0.0f;
    for (int d = tid; d < ND; d += BLK) {
        float v = s_val[d];
        if (v > T) { cgt++; sgt += v; }
    }
    for (int off = 32; off >= 1; off >>= 1) {
        cgt += __shfl_xor(cgt, off, 64);
        sgt += __shfl_xor(sgt, off, 64);
    }
    if (lane == 0) { s_redi[wv] = cgt; s_redf[wv] = sgt; }
    __syncthreads();
    if (tid == 0) {
        int cg = 0; float sg = 0.0f;
        for (int w2 = 0; w2 < NWAVE; ++w2) { cg += s_redi[w2]; sg += s_redf[w2]; }
        int need = k - cg;
        float stk = sg + (float)need * T;
        if (!(T > 0.0f) && need > 0) {
            // T == 0: stable (index-order) selection among zero-valued ce_mined entries.
            // Recompute the ORIGINAL ce for each selected entry (positives: true CE;
            // fp32-underflow negatives: ~0) — matches stable argsort + sum(ce*negf).
            int taken = 0;
            for (int d = 0; d < ND && taken < need; ++d) {
                if (s_val[d] == 0.0f) {
                    const float* cf = conf_data + ((size_t)b * ND + d) * 2;
                    float x0 = cf[0], x1 = cf[1];
                    float m = fmaxf(x0, x1);
                    float lse = m + logf(expf(x0 - m) + expf(x1 - m));
                    unsigned short raw = s_bti[d];
                    bool pos = (raw & 0x8000) != 0;
                    int j = raw & 0x7fff;
                    int lab = pos ? ((int)s_lab[j] + 1) : 0;
                    float ce = lse - (lab >= 1 ? x1 : x0);
                    stk += ce;
                    ++taken;
                }
            }
        }
        g_part[b * 5 + 4] = stk;
    }
}

__global__ void mbl_reduce(float* __restrict__ out) {
    int t = threadIdx.x;  // 64 threads, 1 wave
    float np  = g_part[t * 5 + 0];
    float sl1 = g_part[t * 5 + 1];
    float scp = g_part[t * 5 + 2];
    float kk  = g_part[t * 5 + 3];
    float stk = g_part[t * 5 + 4];
    for (int off = 32; off >= 1; off >>= 1) {
        np  += __shfl_xor(np,  off, 64);
        sl1 += __shfl_xor(sl1, off, 64);
        scp += __shfl_xor(scp, off, 64);
        kk  += __shfl_xor(kk,  off, 64);
        stk += __shfl_xor(stk, off, 64);
    }
    if (t == 0) {
        float loss_l = (np > 0.0f) ? sl1 / (4.0f * np) : 0.0f;
        float lcp    = (np > 0.0f) ? scp / np : 0.0f;
        float lcn    = (kk > 0.0f) ? stk / kk : 0.0f;
        out[0] = loss_l;
        out[1] = lcp + lcn;
        out[2] = lcp;
        out[3] = lcn;
    }
}

extern "C" void kernel_launch(void* const* d_in, const int* in_sizes, int n_in,
                              void* d_out, int out_size, void* d_ws, size_t ws_size,
                              hipStream_t stream) {
    const float* loc     = (const float*)d_in[0];
    const float* conf    = (const float*)d_in[1];
    const float* dboxp   = (const float*)d_in[2];
    const float* targets = (const float*)d_in[3];
    float* out = (float*)d_out;

    mbl_main<<<NB, BLK, 0, stream>>>(loc, conf, dboxp, targets);
    mbl_reduce<<<1, 64, 0, stream>>>(out);
}

// Round 4
// 177.743 us; speedup vs baseline: 1.2462x; 1.2462x over previous
//
#include <hip/hip_runtime.h>

#define NB     64
#define NOBJ   50
#define ND     8732
#define NSPLIT 4
#define RNG    2183            // ND / NSPLIT exactly
#define BLK1   1024
#define ITER1  3               // ceil(RNG / BLK1)
#define BLK2   1024
#define NWAVE2 (BLK2 / 64)
#define CHUNK  10
#define NCHUNK 5

// device-global scratch (rewritten in full every launch; no cross-launch state)
__device__ float              g_part[NB * 5];
__device__ float              g_ov[NB * ND];
__device__ unsigned short     g_idx[NB * ND];
__device__ unsigned long long g_keys[NB * NSPLIT * NOBJ];

// ---------------- K1: IoU + per-prior best (final) + per-truth best (partial per split) ----
__global__ __launch_bounds__(BLK1) void k1_iou(const float* __restrict__ dbox,
                                               const float* __restrict__ targets) {
    __shared__ float s_tx1[NOBJ], s_ty1[NOBJ], s_tx2[NOBJ], s_ty2[NOBJ], s_area[NOBJ];
    __shared__ unsigned long long s_wkey[BLK1 / 64][CHUNK];

    const int blk  = blockIdx.x;
    const int b    = blk / NSPLIT;
    const int spl  = blk % NSPLIT;
    const int tid  = threadIdx.x;
    const int lane = tid & 63;
    const int wv   = tid >> 6;
    const int d0   = spl * RNG;

    if (tid < NOBJ) {
        const float* t = targets + (b * NOBJ + tid) * 5;
        float x1 = t[0], y1 = t[1], x2 = t[2], y2 = t[3];
        s_tx1[tid] = x1; s_ty1[tid] = y1; s_tx2[tid] = x2; s_ty2[tid] = y2;
        s_area[tid] = (x2 - x1) * (y2 - y1);
    }
    __syncthreads();

    // preload this thread's priors (<=3) into registers
    float px1[ITER1], py1[ITER1], px2[ITER1], py2[ITER1], pa[ITER1];
    float bov[ITER1]; int bj[ITER1];
#pragma unroll
    for (int it = 0; it < ITER1; ++it) {
        bov[it] = -1.0f; bj[it] = 0;
        int di = it * BLK1 + tid;
        if (di < RNG) {
            const float* p = dbox + (size_t)(d0 + di) * 4;
            float cx = p[0], cy = p[1], w = p[2], h = p[3];
            px1[it] = cx - 0.5f * w; py1[it] = cy - 0.5f * h;
            px2[it] = cx + 0.5f * w; py2[it] = cy + 0.5f * h;
            pa[it]  = w * h;
        } else {
            px1[it] = 0.f; py1[it] = 0.f; px2[it] = 0.f; py2[it] = 0.f; pa[it] = 0.f;
        }
    }

    for (int c = 0; c < NCHUNK; ++c) {
        float ttx1[CHUNK], tty1[CHUNK], ttx2[CHUNK], tty2[CHUNK], tta[CHUNK];
#pragma unroll
        for (int jj = 0; jj < CHUNK; ++jj) {
            int j = c * CHUNK + jj;
            ttx1[jj] = s_tx1[j]; tty1[jj] = s_ty1[j];
            ttx2[jj] = s_tx2[j]; tty2[jj] = s_ty2[j];
            tta[jj]  = s_area[j];
        }
        unsigned long long key[CHUNK];
#pragma unroll
        for (int jj = 0; jj < CHUNK; ++jj) key[jj] = 0ull;

#pragma unroll
        for (int it = 0; it < ITER1; ++it) {
            int di = it * BLK1 + tid;
            if (di >= RNG) continue;
            unsigned d = (unsigned)(d0 + di);
#pragma unroll
            for (int jj = 0; jj < CHUNK; ++jj) {
                float ltx = fmaxf(ttx1[jj], px1[it]), lty = fmaxf(tty1[jj], py1[it]);
                float rbx = fminf(ttx2[jj], px2[it]), rby = fminf(tty2[jj], py2[it]);
                float ww = fmaxf(rbx - ltx, 0.0f), hh = fmaxf(rby - lty, 0.0f);
                float inter = ww * hh;
                float iou = inter / (tta[jj] + pa[it] - inter);
                if (iou > bov[it]) { bov[it] = iou; bj[it] = c * CHUNK + jj; }
                unsigned long long enc =
                    ((unsigned long long)__float_as_uint(iou) << 32) |
                    (unsigned long long)(0xFFFFFFFFu - d);
                if (enc > key[jj]) key[jj] = enc;
            }
        }
        // block-reduce the per-truth keys
#pragma unroll
        for (int jj = 0; jj < CHUNK; ++jj) {
            unsigned long long k0 = key[jj];
            for (int off = 32; off >= 1; off >>= 1) {
                unsigned long long o = __shfl_xor(k0, off, 64);
                if (o > k0) k0 = o;
            }
            if (lane == 0) s_wkey[wv][jj] = k0;
        }
        __syncthreads();
        if (tid < CHUNK) {
            unsigned long long k0 = s_wkey[0][tid];
            for (int wq = 1; wq < BLK1 / 64; ++wq) {
                unsigned long long o = s_wkey[wq][tid];
                if (o > k0) k0 = o;
            }
            g_keys[(size_t)blk * NOBJ + c * CHUNK + tid] = k0;
        }
        __syncthreads();
    }

    // final per-prior results
#pragma unroll
    for (int it = 0; it < ITER1; ++it) {
        int di = it * BLK1 + tid;
        if (di < RNG) {
            int d = d0 + di;
            g_ov[(size_t)b * ND + d]  = bov[it];
            g_idx[(size_t)b * ND + d] = (unsigned short)bj[it];
        }
    }
}

// ---------------- K2: scatter + encode/L1/CE + radix-select top-k ----------------
__global__ __launch_bounds__(BLK2) void k2_loss(const float* __restrict__ loc_data,
                                                const float* __restrict__ conf_data,
                                                const float* __restrict__ dbox,
                                                const float* __restrict__ targets) {
    __shared__ float s_val[ND];
    __shared__ unsigned short s_bti[ND];
    __shared__ float s_tx1[NOBJ], s_ty1[NOBJ], s_tx2[NOBJ], s_ty2[NOBJ], s_lab[NOBJ];
    __shared__ unsigned int s_dj[NOBJ];
    __shared__ int s_hist[NWAVE2 * 256];
    __shared__ int s_comb[256];
    __shared__ float s_redf[NWAVE2], s_redf2[NWAVE2], s_redf3[NWAVE2];
    __shared__ int s_redi[NWAVE2];
    __shared__ int s_sel, s_krem, s_k;

    const int b    = blockIdx.x;
    const int tid  = threadIdx.x;
    const int lane = tid & 63;
    const int wv   = tid >> 6;

    if (tid < NOBJ) {
        const float* t = targets + (b * NOBJ + tid) * 5;
        s_tx1[tid] = t[0]; s_ty1[tid] = t[1]; s_tx2[tid] = t[2]; s_ty2[tid] = t[3];
        s_lab[tid] = t[4];
        // merge split keys -> final best prior per truth
        unsigned long long k0 = 0ull;
        for (int s = 0; s < NSPLIT; ++s) {
            unsigned long long o = g_keys[((size_t)b * NSPLIT + s) * NOBJ + tid];
            if (o > k0) k0 = o;
        }
        s_dj[tid] = 0xFFFFFFFFu - (unsigned int)(k0 & 0xFFFFFFFFull);
    }
    // stage per-prior (ov, idx)
    for (int d = tid; d < ND; d += BLK2) {
        s_val[d] = g_ov[(size_t)b * ND + d];
        s_bti[d] = g_idx[(size_t)b * ND + d];
    }
    __syncthreads();

    // sequential scatter (last-write-wins over j)
    if (tid == 0) {
#pragma unroll 1
        for (int j = 0; j < NOBJ; ++j) {
            unsigned int d = s_dj[j];
            s_val[d] = 2.0f;
            s_bti[d] = (unsigned short)j;
        }
    }
    __syncthreads();

    // phase 2: encode + smooth-L1 + CE; overwrite s_val with ce_mined
    float npos = 0.0f, sl1 = 0.0f, scep = 0.0f;
    for (int d = tid; d < ND; d += BLK2) {
        float ov = s_val[d];
        int j = (int)s_bti[d];
        bool pos = !(ov < 0.5f);
        const float* cf = conf_data + ((size_t)b * ND + d) * 2;
        float x0 = cf[0], x1 = cf[1];
        float m = fmaxf(x0, x1);
        float lse = m + logf(expf(x0 - m) + expf(x1 - m));
        int lab = pos ? ((int)s_lab[j] + 1) : 0;
        float ce = lse - (lab >= 1 ? x1 : x0);
        s_val[d] = pos ? 0.0f : ce;
        s_bti[d] = (unsigned short)(j | (pos ? 0x8000 : 0));
        if (pos) {
            npos += 1.0f;
            scep += ce;
            const float* p = dbox + (size_t)d * 4;
            float cx = p[0], cy = p[1], w = p[2], h = p[3];
            float tx1 = s_tx1[j], ty1 = s_ty1[j], tx2 = s_tx2[j], ty2 = s_ty2[j];
            float g0 = ((tx1 + tx2) * 0.5f - cx) / (0.1f * w);
            float g1 = ((ty1 + ty2) * 0.5f - cy) / (0.1f * h);
            float g2 = logf((tx2 - tx1) / w) / 0.2f;
            float g3 = logf((ty2 - ty1) / h) / 0.2f;
            const float* ld = loc_data + ((size_t)b * ND + d) * 4;
            float tt[4] = {g0, g1, g2, g3};
#pragma unroll
            for (int q = 0; q < 4; ++q) {
                float dd = fabsf(ld[q] - tt[q]);
                sl1 += (dd < 1.0f) ? 0.5f * dd * dd : dd - 0.5f;
            }
        }
    }
    for (int off = 32; off >= 1; off >>= 1) {
        npos += __shfl_xor(npos, off, 64);
        sl1  += __shfl_xor(sl1,  off, 64);
        scep += __shfl_xor(scep, off, 64);
    }
    if (lane == 0) { s_redf[wv] = npos; s_redf2[wv] = sl1; s_redf3[wv] = scep; }
    __syncthreads();
    if (tid == 0) {
        float a = 0.0f, bb = 0.0f, cc = 0.0f;
        for (int w2 = 0; w2 < NWAVE2; ++w2) { a += s_redf[w2]; bb += s_redf2[w2]; cc += s_redf3[w2]; }
        int np = (int)a;
        int k = np * 3;
        if (k < 20) k = 20;
        if (k > ND) k = ND;
        s_k = k;
        g_part[b * 5 + 0] = a;
        g_part[b * 5 + 1] = bb;
        g_part[b * 5 + 2] = cc;
        g_part[b * 5 + 3] = (float)k;
    }
    __syncthreads();
    const int k = s_k;

    // phase 3: exact k-th largest via 4-pass 8-bit radix select (per-wave histograms)
    unsigned int prefix = 0u, prefmask = 0u;
    int krem = k;
    for (int pass = 0; pass < 4; ++pass) {
        const int shift = 24 - pass * 8;
        for (int i = tid; i < NWAVE2 * 256; i += BLK2) s_hist[i] = 0;
        __syncthreads();
        for (int d = tid; d < ND; d += BLK2) {
            unsigned int vb = __float_as_uint(s_val[d]);
            if ((vb & prefmask) == prefix)
                atomicAdd(&s_hist[wv * 256 + ((vb >> shift) & 255u)], 1);
        }
        __syncthreads();
        if (tid < 256) {
            int s = 0;
            for (int w2 = 0; w2 < NWAVE2; ++w2) s += s_hist[w2 * 256 + tid];
            s_comb[tid] = s;
        }
        __syncthreads();
        if (tid == 0) {
            int cum = 0, B = 0, kr = krem;
            for (int i = 255; i >= 0; --i) {
                cum += s_comb[i];
                if (cum >= kr) { B = i; kr -= (cum - s_comb[i]); break; }
            }
            s_sel = B; s_krem = kr;
        }
        __syncthreads();
        prefix  |= ((unsigned int)s_sel) << shift;
        prefmask |= (255u << shift);
        krem = s_krem;
        __syncthreads();
    }
    float T = __uint_as_float(prefix);

    // strict-greater sum + tie fill
    int cgt = 0; float sgt = 0.0f;
    for (int d = tid; d < ND; d += BLK2) {
        float v = s_val[d];
        if (v > T) { cgt++; sgt += v; }
    }
    for (int off = 32; off >= 1; off >>= 1) {
        cgt += __shfl_xor(cgt, off, 64);
        sgt += __shfl_xor(sgt, off, 64);
    }
    if (lane == 0) { s_redi[wv] = cgt; s_redf[wv] = sgt; }
    __syncthreads();
    if (tid == 0) {
        int cg = 0; float sg = 0.0f;
        for (int w2 = 0; w2 < NWAVE2; ++w2) { cg += s_redi[w2]; sg += s_redf[w2]; }
        int need = k - cg;
        float stk = sg + (float)need * T;
        if (!(T > 0.0f) && need > 0) {
            // T == 0: stable (index-order) selection among zero-valued entries;
            // recompute ORIGINAL ce (positives: true CE; underflow negatives: ~0).
            int taken = 0;
            for (int d = 0; d < ND && taken < need; ++d) {
                if (s_val[d] == 0.0f) {
                    const float* cf = conf_data + ((size_t)b * ND + d) * 2;
                    float x0 = cf[0], x1 = cf[1];
                    float m = fmaxf(x0, x1);
                    float lse = m + logf(expf(x0 - m) + expf(x1 - m));
                    unsigned short raw = s_bti[d];
                    bool pos = (raw & 0x8000) != 0;
                    int j = raw & 0x7fff;
                    int lab = pos ? ((int)s_lab[j] + 1) : 0;
                    float ce = lse - (lab >= 1 ? x1 : x0);
                    stk += ce;
                    ++taken;
                }
            }
        }
        g_part[b * 5 + 4] = stk;
    }
}

// ---------------- K3: final combine ----------------
__global__ void mbl_reduce(float* __restrict__ out) {
    int t = threadIdx.x;  // 64 threads, 1 wave
    float np  = g_part[t * 5 + 0];
    float sl1 = g_part[t * 5 + 1];
    float scp = g_part[t * 5 + 2];
    float kk  = g_part[t * 5 + 3];
    float stk = g_part[t * 5 + 4];
    for (int off = 32; off >= 1; off >>= 1) {
        np  += __shfl_xor(np,  off, 64);
        sl1 += __shfl_xor(sl1, off, 64);
        scp += __shfl_xor(scp, off, 64);
        kk  += __shfl_xor(kk,  off, 64);
        stk += __shfl_xor(stk, off, 64);
    }
    if (t == 0) {
        float loss_l = (np > 0.0f) ? sl1 / (4.0f * np) : 0.0f;
        float lcp    = (np > 0.0f) ? scp / np : 0.0f;
        float lcn    = (kk > 0.0f) ? stk / kk : 0.0f;
        out[0] = loss_l;
        out[1] = lcp + lcn;
        out[2] = lcp;
        out[3] = lcn;
    }
}

extern "C" void kernel_launch(void* const* d_in, const int* in_sizes, int n_in,
                              void* d_out, int out_size, void* d_ws, size_t ws_size,
                              hipStream_t stream) {
    const float* loc     = (const float*)d_in[0];
    const float* conf    = (const float*)d_in[1];
    const float* dboxp   = (const float*)d_in[2];
    const float* targets = (const float*)d_in[3];
    float* out = (float*)d_out;

    k1_iou<<<NB * NSPLIT, BLK1, 0, stream>>>(dboxp, targets);
    k2_loss<<<NB, BLK2, 0, stream>>>(loc, conf, dboxp, targets);
    mbl_reduce<<<1, 64, 0, stream>>>(out);
}

// Round 5
// 139.588 us; speedup vs baseline: 1.5869x; 1.2733x over previous
//
#include <hip/hip_runtime.h>

#define NB     64
#define NOBJ   50
#define ND     8732
#define PPT    3
#define BLK1   256
#define PRB    (BLK1*PPT)                 // 768 priors per k1 block
#define NSPLIT ((ND + PRB - 1) / PRB)     // 12
#define NW1    (BLK1/64)                  // 4 waves
#define CHUNK  10
#define NCHUNK 5
#define BLK2   1024
#define NW2    (BLK2/64)                  // 16 waves
#define ITER2  ((ND + BLK2 - 1)/BLK2)     // 9

// device scratch — every slot rewritten each launch (graph-replay safe)
__device__ float              g_part[NB*5];
__device__ float              g_ov[(size_t)NB*ND];
__device__ unsigned short     g_idx[(size_t)NB*ND];
__device__ unsigned long long g_keys[(size_t)NB*NSPLIT*NW1*NOBJ];
__device__ int                g_done;

// ---------------- K1: IoU, per-prior best truth, per-truth best prior (per-wave partials) ----
__global__ __launch_bounds__(BLK1) void k1_iou(const float* __restrict__ dbox,
                                               const float* __restrict__ targets) {
    __shared__ float s_tx1[NOBJ], s_ty1[NOBJ], s_tx2[NOBJ], s_ty2[NOBJ], s_area[NOBJ];
    const int blk  = blockIdx.x;
    const int b    = blk / NSPLIT;
    const int spl  = blk % NSPLIT;
    const int tid  = threadIdx.x;
    const int lane = tid & 63;
    const int wv   = tid >> 6;

    if (blk == 0 && tid == 0) g_done = 0;   // reset finisher ticket (k1 completes before k2 starts)

    if (tid < NOBJ) {
        const float* t = targets + (b*NOBJ + tid)*5;
        float x1=t[0], y1=t[1], x2=t[2], y2=t[3];
        s_tx1[tid]=x1; s_ty1[tid]=y1; s_tx2[tid]=x2; s_ty2[tid]=y2;
        s_area[tid]=(x2-x1)*(y2-y1);
    }
    __syncthreads();

    const int d0  = spl * PRB;
    const int cnt = (ND - d0 < PRB) ? (ND - d0) : PRB;

    // contiguous mapping: lane order == d order (needed for ballot tie-break)
    float px1[PPT], py1[PPT], px2[PPT], py2[PPT], pa[PPT];
    bool  vld[PPT];
    float bov[PPT]; int bj[PPT];
#pragma unroll
    for (int q = 0; q < PPT; ++q) {
        int dl = tid*PPT + q;
        vld[q] = dl < cnt;
        bov[q] = -1.0f; bj[q] = 0;
        px1[q]=py1[q]=px2[q]=py2[q]=0.f; pa[q]=0.f;
        if (vld[q]) {
            float4 p = reinterpret_cast<const float4*>(dbox)[d0 + dl];
            px1[q] = p.x - 0.5f*p.z; py1[q] = p.y - 0.5f*p.w;
            px2[q] = p.x + 0.5f*p.z; py2[q] = p.y + 0.5f*p.w;
            pa[q]  = p.z * p.w;
        }
    }

    unsigned long long* kout = g_keys + (((size_t)b*NSPLIT + spl)*NW1 + wv)*NOBJ;

    for (int c = 0; c < NCHUNK; ++c) {
        float ttx1[CHUNK],tty1[CHUNK],ttx2[CHUNK],tty2[CHUNK],tta[CHUNK];
#pragma unroll
        for (int jj=0;jj<CHUNK;++jj){ int j=c*CHUNK+jj;
            ttx1[jj]=s_tx1[j]; tty1[jj]=s_ty1[j]; ttx2[jj]=s_tx2[j]; tty2[jj]=s_ty2[j]; tta[jj]=s_area[j]; }
        float tb[CHUNK]; int td[CHUNK];
#pragma unroll
        for (int jj=0;jj<CHUNK;++jj){ tb[jj]=-1.0f; td[jj]=0; }

#pragma unroll
        for (int q=0;q<PPT;++q){
            if (!vld[q]) continue;
            const int d = d0 + tid*PPT + q;
#pragma unroll
            for (int jj=0;jj<CHUNK;++jj){
                float ltx=fmaxf(ttx1[jj],px1[q]), lty=fmaxf(tty1[jj],py1[q]);
                float rbx=fminf(ttx2[jj],px2[q]), rby=fminf(tty2[jj],py2[q]);
                float ww=fmaxf(rbx-ltx,0.f), hh=fmaxf(rby-lty,0.f);
                float inter=ww*hh;
                float iou=__fdividef(inter, tta[jj]+pa[q]-inter);
                if (iou>bov[q]){bov[q]=iou;bj[q]=c*CHUNK+jj;}   // strict > : first max (smallest j)
                if (iou>tb[jj]){tb[jj]=iou;td[jj]=d;}           // strict > : smallest d within lane
            }
        }
        // per-truth wave argmax: float max + ballot (lowest lane = smallest d) + readlane
#pragma unroll
        for (int jj=0;jj<CHUNK;++jj){
            float m = tb[jj];
#pragma unroll
            for (int off=32; off>=1; off>>=1)
                m = fmaxf(m, __shfl_xor(m, off, 64));
            unsigned long long msk = __ballot(tb[jj]==m);
            int lead = __builtin_ctzll(msk);
            int dwin = __shfl(td[jj], lead, 64);
            if (lane==0) {
                unsigned long long enc = (m>=0.f)
                  ? (((unsigned long long)__float_as_uint(m)<<32)
                     | (unsigned long long)(0xFFFFFFFFu - (unsigned)dwin))
                  : 0ull;   // fully-idle wave (last split tail): never wins the merge
                kout[c*CHUNK+jj] = enc;
            }
        }
    }
#pragma unroll
    for (int q=0;q<PPT;++q){
        if (vld[q]) {
            int d = d0 + tid*PPT + q;
            g_ov [(size_t)b*ND + d] = bov[q];
            g_idx[(size_t)b*ND + d] = (unsigned short)bj[q];
        }
    }
}

// ---------------- K2: scatter + encode/L1/CE + parallel radix select + fused finisher ----
__global__ __launch_bounds__(BLK2) void k2_loss(const float* __restrict__ loc_data,
                                                const float* __restrict__ conf_data,
                                                const float* __restrict__ dbox,
                                                const float* __restrict__ targets,
                                                float* __restrict__ out) {
    __shared__ float s_tx1[NOBJ],s_ty1[NOBJ],s_tx2[NOBJ],s_ty2[NOBJ],s_lab[NOBJ];
    __shared__ unsigned int   s_dj[NOBJ];
    __shared__ unsigned short s_ovr[ND];   // 0xFFFF = no override, else truth idx (forced match)
    __shared__ float s_val[ND];            // ce_mined (for rare T==0 fallback)
    __shared__ int   s_hist[NW2*256];
    __shared__ int   s_wtot[4];
    __shared__ float s_rf[NW2], s_rf2[NW2], s_rf3[NW2];
    __shared__ int   s_ri[NW2];
    __shared__ int   s_sel, s_krem, s_kk, s_last;

    const int b=blockIdx.x, tid=threadIdx.x, lane=tid&63, wv=tid>>6;

    for (int i=tid;i<ND;i+=BLK2) s_ovr[i]=0xFFFFu;
    if (tid<NOBJ){
        const float* t=targets+(b*NOBJ+tid)*5;
        s_tx1[tid]=t[0]; s_ty1[tid]=t[1]; s_tx2[tid]=t[2]; s_ty2[tid]=t[3]; s_lab[tid]=t[4];
        unsigned long long k0=0ull;
        const unsigned long long* kp = g_keys + (size_t)b*NSPLIT*NW1*NOBJ + tid;
#pragma unroll 1
        for (int s=0;s<NSPLIT*NW1;++s){ unsigned long long o=kp[(size_t)s*NOBJ]; if(o>k0)k0=o; }
        s_dj[tid]=0xFFFFFFFFu-(unsigned)(k0&0xFFFFFFFFull);
    }
    __syncthreads();
    // parallel last-write-wins scatter: thread j wins iff no j' > j shares its prior
    if (tid<NOBJ){
        unsigned d=s_dj[tid]; bool win=true;
        for (int j2=tid+1;j2<NOBJ;++j2) if (s_dj[j2]==d){win=false;break;}
        if (win) s_ovr[d]=(unsigned short)tid;
    }
    __syncthreads();

    // phase 2: encode + smooth-L1 + CE; ce_mined kept in registers
    float ce[ITER2];
    float npos=0.f, sl1=0.f, scep=0.f;
#pragma unroll
    for (int it=0; it<ITER2; ++it){
        int d = tid + it*BLK2;
        float cm = 0.f;
        if (d < ND) {
            float ov = g_ov[(size_t)b*ND+d];
            int j    = (int)g_idx[(size_t)b*ND+d];
            unsigned short ovr = s_ovr[d];
            if (ovr != 0xFFFFu){ ov=2.0f; j=(int)ovr; }
            bool pos = !(ov < 0.5f);
            float2 cf = reinterpret_cast<const float2*>(conf_data)[(size_t)b*ND+d];
            float m = fmaxf(cf.x, cf.y);
            float lse = m + __logf(__expf(cf.x-m)+__expf(cf.y-m));
            int lab = pos ? ((int)s_lab[j] + 1) : 0;
            float ced = lse - (lab>=1 ? cf.y : cf.x);
            cm = pos ? 0.f : ced;
            if (pos){
                npos += 1.f; scep += ced;
                float4 p = reinterpret_cast<const float4*>(dbox)[d];
                float tx1=s_tx1[j],ty1=s_ty1[j],tx2=s_tx2[j],ty2=s_ty2[j];
                float g0=((tx1+tx2)*0.5f-p.x)/(0.1f*p.z);
                float g1=((ty1+ty2)*0.5f-p.y)/(0.1f*p.w);
                float g2=__logf((tx2-tx1)/p.z)*5.0f;   // /0.2
                float g3=__logf((ty2-ty1)/p.w)*5.0f;
                float4 ld = reinterpret_cast<const float4*>(loc_data)[(size_t)b*ND+d];
                float t0=fabsf(ld.x-g0),t1=fabsf(ld.y-g1),t2=fabsf(ld.z-g2),t3=fabsf(ld.w-g3);
                sl1 += (t0<1.f?0.5f*t0*t0:t0-0.5f) + (t1<1.f?0.5f*t1*t1:t1-0.5f)
                     + (t2<1.f?0.5f*t2*t2:t2-0.5f) + (t3<1.f?0.5f*t3*t3:t3-0.5f);
            }
            s_val[d]=cm;
        }
        ce[it]=cm;
    }
#pragma unroll
    for (int off=32;off>=1;off>>=1){
        npos+=__shfl_xor(npos,off,64);
        sl1 +=__shfl_xor(sl1 ,off,64);
        scep+=__shfl_xor(scep,off,64);
    }
    if (lane==0){s_rf[wv]=npos;s_rf2[wv]=sl1;s_rf3[wv]=scep;}
    __syncthreads();
    if (tid==0){
        float a=0,bb=0,cc=0;
        for(int w2=0;w2<NW2;++w2){a+=s_rf[w2];bb+=s_rf2[w2];cc+=s_rf3[w2];}
        int np=(int)a; int k=np*3; if(k<20)k=20; if(k>ND)k=ND;
        s_kk=k;
        g_part[b*5+0]=a; g_part[b*5+1]=bb; g_part[b*5+2]=cc; g_part[b*5+3]=(float)k;
    }
    __syncthreads();
    const int k = s_kk;

    // phase 3: 3-pass 8-bit radix select (24-bit threshold), fully parallel bucket scan
    unsigned prefix=0u, pmask=0u; int krem=k;
    for (int p=0;p<3;++p){
        const int shift = 24 - p*8;
        for (int i=tid;i<NW2*256;i+=BLK2) s_hist[i]=0;
        __syncthreads();
#pragma unroll
        for (int it=0;it<ITER2;++it){
            int d = tid + it*BLK2;
            if (d<ND){
                unsigned vb=__float_as_uint(ce[it]);
                if ((vb&pmask)==prefix)
                    atomicAdd(&s_hist[wv*256 + (int)((vb>>shift)&255u)],1);
            }
        }
        __syncthreads();
        int cnt=0, S=0, add=0;
        if (tid<256){
            for (int w2=0;w2<NW2;++w2) cnt+=s_hist[w2*256+tid];
            S=cnt;
#pragma unroll
            for (int off=1;off<64;off<<=1){           // inclusive suffix sum within wave
                int t=__shfl_down(S,off,64);
                if (lane+off<64) S+=t;
            }
            if (lane==0) s_wtot[wv]=S;                // wave total
        }
        __syncthreads();
        if (tid<256){
            for (int w2=wv+1;w2<4;++w2) add+=s_wtot[w2];
            S+=add;                                    // true inclusive suffix S[tid]
            int Snext=__shfl_down(S,1,64);
            if (lane==63) Snext=add;                   // S[tid+1] across wave boundary (tid==255 -> 0)
            if (S>=krem && Snext<krem){ s_sel=tid; s_krem=krem-(S-cnt); }
        }
        __syncthreads();
        prefix |= ((unsigned)s_sel)<<shift;
        pmask  |= 255u<<shift;
        krem = s_krem;
    }
    const float T=__uint_as_float(prefix);

    int cgt=0; float sgt=0.f;
#pragma unroll
    for (int it=0;it<ITER2;++it){
        int d=tid+it*BLK2;
        if (d<ND){ float v=ce[it]; if (v>T){cgt++; sgt+=v;} }
    }
#pragma unroll
    for (int off=32;off>=1;off>>=1){ cgt+=__shfl_xor(cgt,off,64); sgt+=__shfl_xor(sgt,off,64); }
    if (lane==0){ s_ri[wv]=cgt; s_rf[wv]=sgt; }
    __syncthreads();
    if (tid==0){
        int cg=0; float sg=0.f;
        for(int w2=0;w2<NW2;++w2){cg+=s_ri[w2];sg+=s_rf[w2];}
        int need=k-cg;
        float stk=sg+(float)need*T;
        if (!(T>0.f) && need>0){
            // T==0: stable index-order selection among zero ce_mined; add ORIGINAL ce
            int taken=0;
            for (int d=0; d<ND && taken<need; ++d){
                if (s_val[d]==0.f){
                    float ov=g_ov[(size_t)b*ND+d]; int j=(int)g_idx[(size_t)b*ND+d];
                    unsigned short ovr=s_ovr[d];
                    if (ovr!=0xFFFFu){ov=2.f;j=(int)ovr;}
                    bool pos=!(ov<0.5f);
                    float2 cf=reinterpret_cast<const float2*>(conf_data)[(size_t)b*ND+d];
                    float m=fmaxf(cf.x,cf.y);
                    float lse=m+__logf(__expf(cf.x-m)+__expf(cf.y-m));
                    int lab=pos?((int)s_lab[j]+1):0;
                    stk += lse-(lab>=1?cf.y:cf.x);
                    ++taken;
                }
            }
        }
        g_part[b*5+4]=stk;
    }

    // fused finisher: last block to arrive combines all 64 batches
    if (tid==0){ __threadfence(); int old=atomicAdd(&g_done,1); s_last=(old==NB-1)?1:0; }
    __syncthreads();
    if (s_last && tid<NB){
        __threadfence();
        volatile float* gp = g_part;
        float np=gp[tid*5+0], sl=gp[tid*5+1], sc=gp[tid*5+2], kk=gp[tid*5+3], st=gp[tid*5+4];
#pragma unroll
        for (int off=32;off>=1;off>>=1){
            np+=__shfl_xor(np,off,64); sl+=__shfl_xor(sl,off,64);
            sc+=__shfl_xor(sc,off,64); kk+=__shfl_xor(kk,off,64); st+=__shfl_xor(st,off,64);
        }
        if (tid==0){
            float loss_l=(np>0.f)?sl/(4.f*np):0.f;
            float lcp=(np>0.f)?sc/np:0.f;
            float lcn=(kk>0.f)?st/kk:0.f;
            out[0]=loss_l; out[1]=lcp+lcn; out[2]=lcp; out[3]=lcn;
        }
    }
}

extern "C" void kernel_launch(void* const* d_in, const int* in_sizes, int n_in,
                              void* d_out, int out_size, void* d_ws, size_t ws_size,
                              hipStream_t stream) {
    const float* loc     = (const float*)d_in[0];
    const float* conf    = (const float*)d_in[1];
    const float* dboxp   = (const float*)d_in[2];
    const float* targets = (const float*)d_in[3];
    float* out = (float*)d_out;

    k1_iou<<<NB*NSPLIT, BLK1, 0, stream>>>(dboxp, targets);
    k2_loss<<<NB, BLK2, 0, stream>>>(loc, conf, dboxp, targets, out);
}

// Round 6
// 123.491 us; speedup vs baseline: 1.7937x; 1.1304x over previous
//
#include <hip/hip_runtime.h>

#define NB     64
#define NOBJ   50
#define ND     8732
#define PPT    3
#define BLK1   256
#define PRB    (BLK1*PPT)            // 768 priors / k1 block
#define NSPLIT 12                    // ceil(8732/768)
#define NW1    (BLK1/64)             // 4
#define NPART  (NSPLIT*NW1)          // 48 key partials per batch
#define CHUNK  10
#define NCHUNK 5
#define BLK2   1024
#define NW2    (BLK2/64)             // 16
#define ITER2  ((ND+BLK2-1)/BLK2)    // 9
#define ND4    (ND/4)                // 2183

// device scratch — every element rewritten each launch (graph-replay safe, deterministic)
__device__ float              g_part[NB*5];
__device__ float4             g_ce4[(size_t)NB*ND4];          // signed ce_mined (pos -> -ce_pos)
__device__ unsigned long long g_keys[(size_t)NB*NPART*NOBJ];
__device__ int                g_hist[(size_t)NB*NSPLIT*256];
__device__ float              g_bp[NB*NSPLIT*3];              // per-split npos/sl1/scep
__device__ int                g_done;

// bit-exact IoU (contraction-proof: used by k1 main loop AND k2 corrections)
__device__ __forceinline__ float iou_rn(float px1,float py1,float px2,float py2,float pa,
                                        float tx1,float ty1,float tx2,float ty2,float ta){
    float ltx=fmaxf(tx1,px1), lty=fmaxf(ty1,py1);
    float rbx=fminf(tx2,px2), rby=fminf(ty2,py2);
    float ww=fmaxf(__fsub_rn(rbx,ltx),0.f), hh=fmaxf(__fsub_rn(rby,lty),0.f);
    float inter=__fmul_rn(ww,hh);
    return __fdividef(inter, __fsub_rn(__fadd_rn(ta,pa),inter));
}
__device__ __forceinline__ float lse2(float x0,float x1){
    float m=fmaxf(x0,x1);
    return m+__logf(__expf(x0-m)+__expf(x1-m));
}
__device__ __forceinline__ float sl1_enc(float4 p,float tx1,float ty1,float tx2,float ty2,float4 ld){
    float g0=((tx1+tx2)*0.5f-p.x)/(0.1f*p.z);
    float g1=((ty1+ty2)*0.5f-p.y)/(0.1f*p.w);
    float g2=__logf((tx2-tx1)/p.z)*5.0f;
    float g3=__logf((ty2-ty1)/p.w)*5.0f;
    float t0=fabsf(ld.x-g0),t1=fabsf(ld.y-g1),t2=fabsf(ld.z-g2),t3=fabsf(ld.w-g3);
    return (t0<1.f?0.5f*t0*t0:t0-0.5f)+(t1<1.f?0.5f*t1*t1:t1-0.5f)
          +(t2<1.f?0.5f*t2*t2:t2-0.5f)+(t3<1.f?0.5f*t3*t3:t3-0.5f);
}

// ---------------- K1: IoU + argmaxes + CE/L1/hist (no-override view) ----------------
__global__ __launch_bounds__(BLK1) void k1(const float* __restrict__ loc_data,
                                           const float* __restrict__ conf_data,
                                           const float* __restrict__ dbox,
                                           const float* __restrict__ targets){
    __shared__ float s_tx1[NOBJ],s_ty1[NOBJ],s_tx2[NOBJ],s_ty2[NOBJ],s_ta[NOBJ],s_lab[NOBJ];
    __shared__ int   s_wh[NW1*256];
    __shared__ float s_r1[NW1],s_r2[NW1],s_r3[NW1];
    const int blk=blockIdx.x, b=blk/NSPLIT, spl=blk%NSPLIT;
    const int tid=threadIdx.x, lane=tid&63, wv=tid>>6;
    if (blk==0 && tid==0) g_done=0;
    if (tid<NOBJ){
        const float* t=targets+(b*NOBJ+tid)*5;
        float x1=t[0],y1=t[1],x2=t[2],y2=t[3];
        s_tx1[tid]=x1;s_ty1[tid]=y1;s_tx2[tid]=x2;s_ty2[tid]=y2;
        s_ta[tid]=__fmul_rn(__fsub_rn(x2,x1),__fsub_rn(y2,y1));
        s_lab[tid]=t[4];
    }
    for (int i=tid;i<NW1*256;i+=BLK1) s_wh[i]=0;
    __syncthreads();

    const int d0=spl*PRB;
    const int cnt=(ND-d0<PRB)?(ND-d0):PRB;
    float px1[PPT],py1[PPT],px2[PPT],py2[PPT],pa[PPT];
    bool vld[PPT]; float bov[PPT]; int bj[PPT];
#pragma unroll
    for (int q=0;q<PPT;++q){
        int dl=tid*PPT+q; vld[q]=dl<cnt; bov[q]=-1.f; bj[q]=0;
        px1[q]=py1[q]=px2[q]=py2[q]=pa[q]=0.f;
        if (vld[q]){
            float4 p=reinterpret_cast<const float4*>(dbox)[d0+dl];
            float hw=__fmul_rn(0.5f,p.z), hh=__fmul_rn(0.5f,p.w);
            px1[q]=__fsub_rn(p.x,hw); py1[q]=__fsub_rn(p.y,hh);
            px2[q]=__fadd_rn(p.x,hw); py2[q]=__fadd_rn(p.y,hh);
            pa[q]=__fmul_rn(p.z,p.w);
        }
    }
    unsigned long long* kout=g_keys+(((size_t)b*NSPLIT+spl)*NW1+wv)*NOBJ;

    for (int c=0;c<NCHUNK;++c){
        float tx1c[CHUNK],ty1c[CHUNK],tx2c[CHUNK],ty2c[CHUNK],tac[CHUNK];
#pragma unroll
        for (int jj=0;jj<CHUNK;++jj){int j=c*CHUNK+jj;
            tx1c[jj]=s_tx1[j];ty1c[jj]=s_ty1[j];tx2c[jj]=s_tx2[j];ty2c[jj]=s_ty2[j];tac[jj]=s_ta[j];}
        float tb[CHUNK]; int td[CHUNK];
#pragma unroll
        for (int jj=0;jj<CHUNK;++jj){tb[jj]=-1.f;td[jj]=0;}
#pragma unroll
        for (int q=0;q<PPT;++q){
            if (!vld[q]) continue;
            const int d=d0+tid*PPT+q;
#pragma unroll
            for (int jj=0;jj<CHUNK;++jj){
                float iou=iou_rn(px1[q],py1[q],px2[q],py2[q],pa[q],
                                 tx1c[jj],ty1c[jj],tx2c[jj],ty2c[jj],tac[jj]);
                if (iou>bov[q]){bov[q]=iou;bj[q]=c*CHUNK+jj;}   // first-max (smallest j)
                if (iou>tb[jj]){tb[jj]=iou;td[jj]=d;}           // smallest d within lane
            }
        }
#pragma unroll
        for (int jj=0;jj<CHUNK;++jj){
            float m=tb[jj];
#pragma unroll
            for (int off=32;off>=1;off>>=1) m=fmaxf(m,__shfl_xor(m,off,64));
            unsigned long long msk=__ballot(tb[jj]==m);
            int lead=__builtin_ctzll(msk);                       // lowest lane = smallest d
            int dwin=__shfl(td[jj],lead,64);
            if (lane==0){
                unsigned long long enc=(m>=0.f)
                    ?(((unsigned long long)__float_as_uint(m)<<32)
                      |(unsigned long long)(0xFFFFFFFFu-(unsigned)dwin))
                    :0ull;                                       // fully-idle tail wave
                kout[c*CHUNK+jj]=enc;
            }
        }
    }

    // phase 2 (no-override view): CE, L1, signed ce_mined, histogram
    float* gce=(float*)g_ce4;
    float np=0.f,sl=0.f,sc=0.f;
#pragma unroll
    for (int q=0;q<PPT;++q){
        if (!vld[q]) continue;
        const int d=d0+tid*PPT+q;
        float2 cf=reinterpret_cast<const float2*>(conf_data)[(size_t)b*ND+d];
        float l=lse2(cf.x,cf.y);
        bool pos=!(bov[q]<0.5f);
        int jb=bj[q];
        int lab=pos?((int)s_lab[jb]+1):0;
        float cev=l-(lab>=1?cf.y:cf.x);
        float raw=pos?-cev:cev;                   // sign flags positive-masked entries
        gce[(size_t)b*ND+d]=raw;
        atomicAdd(&s_wh[wv*256+(int)(__float_as_uint(fmaxf(raw,0.f))>>24)],1);
        if (pos){
            np+=1.f; sc+=cev;
            float4 p=reinterpret_cast<const float4*>(dbox)[d];
            float4 ldv=reinterpret_cast<const float4*>(loc_data)[(size_t)b*ND+d];
            sl+=sl1_enc(p,s_tx1[jb],s_ty1[jb],s_tx2[jb],s_ty2[jb],ldv);
        }
    }
#pragma unroll
    for (int off=32;off>=1;off>>=1){
        np+=__shfl_xor(np,off,64); sl+=__shfl_xor(sl,off,64); sc+=__shfl_xor(sc,off,64);
    }
    if (lane==0){s_r1[wv]=np;s_r2[wv]=sl;s_r3[wv]=sc;}
    __syncthreads();
    if (tid==0){
        float a=0.f,bb2=0.f,cc=0.f;
        for (int w=0;w<NW1;++w){a+=s_r1[w];bb2+=s_r2[w];cc+=s_r3[w];}
        g_bp[(b*NSPLIT+spl)*3+0]=a;
        g_bp[(b*NSPLIT+spl)*3+1]=bb2;
        g_bp[(b*NSPLIT+spl)*3+2]=cc;
    }
    {
        int s=0;
        for (int w=0;w<NW1;++w) s+=s_wh[w*256+tid];
        g_hist[(size_t)(b*NSPLIT+spl)*256+tid]=s;
    }
}

// ---------------- K2: merge + corrections + radix select + fused finisher ----------------
__global__ __launch_bounds__(BLK2) void k2(const float* __restrict__ loc_data,
                                           const float* __restrict__ conf_data,
                                           const float* __restrict__ dbox,
                                           const float* __restrict__ targets,
                                           float* __restrict__ out){
    __shared__ float4 s_ce4[ND4];
    __shared__ unsigned long long s_km[NOBJ*16];
    __shared__ unsigned int s_dj[NOBJ];
    __shared__ float s_tx1[NOBJ],s_ty1[NOBJ],s_tx2[NOBJ],s_ty2[NOBJ],s_ta[NOBJ],s_lab[NOBJ];
    __shared__ int   s_hist[256];
    __shared__ int   s_wh[NW2*256];
    __shared__ float s_bpl[NSPLIT*3];
    __shared__ float s_rf[NW2]; __shared__ int s_ri[NW2];
    __shared__ int   s_wt[4];
    __shared__ float s_dnp,s_dsl,s_dsc;
    __shared__ int   s_sel,s_krem,s_kk,s_last;
    float* s_ce=(float*)s_ce4;

    const int b=blockIdx.x, tid=threadIdx.x, lane=tid&63, wv=tid>>6;

    if (tid<NOBJ){
        const float* t=targets+(b*NOBJ+tid)*5;
        float x1=t[0],y1=t[1],x2=t[2],y2=t[3];
        s_tx1[tid]=x1;s_ty1[tid]=y1;s_tx2[tid]=x2;s_ty2[tid]=y2;
        s_ta[tid]=__fmul_rn(__fsub_rn(x2,x1),__fsub_rn(y2,y1));
        s_lab[tid]=t[4];
    }
    if (tid<NOBJ*16){                    // parallel key merge: 3 loads/thread
        int j=tid>>4, s=tid&15;
        const unsigned long long* kp=g_keys+(size_t)b*NPART*NOBJ;
        unsigned long long m=kp[(size_t)s*NOBJ+j];
        unsigned long long o=kp[(size_t)(s+16)*NOBJ+j]; if(o>m)m=o;
        o=kp[(size_t)(s+32)*NOBJ+j]; if(o>m)m=o;
        s_km[tid]=m;
    }
    for (int i=tid;i<ND4;i+=BLK2) s_ce4[i]=g_ce4[(size_t)b*ND4+i];
    if (tid<256){
        int s=0;
        for (int sp=0;sp<NSPLIT;++sp) s+=g_hist[(size_t)(b*NSPLIT+sp)*256+tid];
        s_hist[tid]=s;
    }
    if (tid<NSPLIT*3) s_bpl[tid]=g_bp[b*NSPLIT*3+tid];
    __syncthreads();
    if (tid<NOBJ){
        unsigned long long m=s_km[tid*16];
        for (int s=1;s<16;++s){unsigned long long o=s_km[tid*16+s]; if(o>m)m=o;}
        s_dj[tid]=0xFFFFFFFFu-(unsigned)(m&0xFFFFFFFFull);
    }
    __syncthreads();

    // override corrections (<=50 priors forced positive, last-write-wins)
    float dnp=0.f,dsl=0.f,dsc=0.f;
    if (tid<NOBJ){
        unsigned d=s_dj[tid]; bool win=true;
        for (int j2=tid+1;j2<NOBJ;++j2) if (s_dj[j2]==d){win=false;break;}
        if (win){
            float4 p=reinterpret_cast<const float4*>(dbox)[d];
            float hw=__fmul_rn(0.5f,p.z), hh2=__fmul_rn(0.5f,p.w);
            float ppx1=__fsub_rn(p.x,hw),ppy1=__fsub_rn(p.y,hh2);
            float ppx2=__fadd_rn(p.x,hw),ppy2=__fadd_rn(p.y,hh2);
            float ppa=__fmul_rn(p.z,p.w);
            float bov=-1.f; int jb=0;
            for (int j=0;j<NOBJ;++j){     // bit-identical recompute of k1's match
                float iou=iou_rn(ppx1,ppy1,ppx2,ppy2,ppa,
                                 s_tx1[j],s_ty1[j],s_tx2[j],s_ty2[j],s_ta[j]);
                if (iou>bov){bov=iou;jb=j;}
            }
            bool oldpos=!(bov<0.5f);
            float2 cf=reinterpret_cast<const float2*>(conf_data)[(size_t)b*ND+d];
            float l=lse2(cf.x,cf.y);
            float4 ldv=reinterpret_cast<const float4*>(loc_data)[(size_t)b*ND+d];
            int labN=(int)s_lab[tid]+1;
            float ceN=l-(labN>=1?cf.y:cf.x);
            dsc+=ceN; dsl+=sl1_enc(p,s_tx1[tid],s_ty1[tid],s_tx2[tid],s_ty2[tid],ldv);
            if (oldpos){
                int labO=(int)s_lab[jb]+1;
                float ceO=l-(labO>=1?cf.y:cf.x);
                dsc-=ceO; dsl-=sl1_enc(p,s_tx1[jb],s_ty1[jb],s_tx2[jb],s_ty2[jb],ldv);
            } else dnp+=1.f;
            float oldraw=s_ce[d];
            atomicAdd(&s_hist[(int)(__float_as_uint(fmaxf(oldraw,0.f))>>24)],-1);
            atomicAdd(&s_hist[0],1);
            s_ce[d]=-ceN;
        }
    }
    if (wv==0){
#pragma unroll
        for (int off=32;off>=1;off>>=1){
            dnp+=__shfl_xor(dnp,off,64); dsl+=__shfl_xor(dsl,off,64); dsc+=__shfl_xor(dsc,off,64);
        }
        if (lane==0){s_dnp=dnp;s_dsl=dsl;s_dsc=dsc;}
    }
    __syncthreads();
    if (tid==0){
        float np=s_dnp, sl=s_dsl, sc=s_dsc;
        for (int i=0;i<NSPLIT;++i){np+=s_bpl[i*3];sl+=s_bpl[i*3+1];sc+=s_bpl[i*3+2];}
        int npi=(int)np; int k=npi*3; if(k<20)k=20; if(k>ND)k=ND;
        s_kk=k;
        g_part[b*5+0]=np; g_part[b*5+1]=sl; g_part[b*5+2]=sc; g_part[b*5+3]=(float)k;
    }
    __syncthreads();
    const int k=s_kk;

    // radix select: pass 1 free from histogram; passes 2-3 scan LDS
    unsigned prefix=0u,pmask=0u; int krem=k;
    for (int p=0;p<3;++p){
        const int shift=24-p*8;
        int cnt=0;
        if (p==0){
            if (tid<256) cnt=s_hist[tid];
        } else {
            for (int i=tid;i<NW2*256;i+=BLK2) s_wh[i]=0;
            __syncthreads();
            for (int it=0;it<ITER2;++it){
                int d=tid+it*BLK2;
                if (d<ND){
                    unsigned vb=__float_as_uint(fmaxf(s_ce[d],0.f));
                    if ((vb&pmask)==prefix)
                        atomicAdd(&s_wh[wv*256+(int)((vb>>shift)&255u)],1);
                }
            }
            __syncthreads();
            if (tid<256){
                for (int w=0;w<NW2;++w) cnt+=s_wh[w*256+tid];
            }
        }
        int S=cnt,add=0;
        if (tid<256){
#pragma unroll
            for (int off=1;off<64;off<<=1){
                int t=__shfl_down(S,off,64);
                if (lane+off<64) S+=t;
            }
            if (lane==0) s_wt[wv]=S;
        }
        __syncthreads();
        if (tid<256){
            for (int w=wv+1;w<4;++w) add+=s_wt[w];
            S+=add;
            int Snext=__shfl_down(S,1,64);
            if (lane==63) Snext=add;
            if (S>=krem && Snext<krem){s_sel=tid;s_krem=krem-(S-cnt);}
        }
        __syncthreads();
        prefix|=((unsigned)s_sel)<<shift;
        pmask|=255u<<shift;
        krem=s_krem;
        __syncthreads();
    }
    const float T=__uint_as_float(prefix);

    int cgt=0; float sgt=0.f;
    for (int it=0;it<ITER2;++it){
        int d=tid+it*BLK2;
        if (d<ND){
            float v=fmaxf(s_ce[d],0.f);
            if (v>T){cgt++;sgt+=v;}
        }
    }
#pragma unroll
    for (int off=32;off>=1;off>>=1){cgt+=__shfl_xor(cgt,off,64);sgt+=__shfl_xor(sgt,off,64);}
    if (lane==0){s_ri[wv]=cgt;s_rf[wv]=sgt;}
    __syncthreads();
    if (tid==0){
        int cg=0; float sg=0.f;
        for (int w=0;w<NW2;++w){cg+=s_ri[w];sg+=s_rf[w];}
        int need=k-cg;
        float stk=sg+(float)need*T;
        if (!(T>0.f)&&need>0){
            // T==0: stable index-order tie pool = {raw<=0}; original ce = |raw|
            int taken=0;
            for (int d=0;d<ND&&taken<need;++d){
                float r=s_ce[d];
                if (!(r>0.f)){stk+=fabsf(r);++taken;}
            }
        }
        g_part[b*5+4]=stk;
    }

    if (tid==0){__threadfence(); int old=atomicAdd(&g_done,1); s_last=(old==NB-1)?1:0;}
    __syncthreads();
    if (s_last&&tid<NB){
        __threadfence();
        volatile float* gp=g_part;
        float np=gp[tid*5+0],sl=gp[tid*5+1],sc=gp[tid*5+2],kk=gp[tid*5+3],st=gp[tid*5+4];
#pragma unroll
        for (int off=32;off>=1;off>>=1){
            np+=__shfl_xor(np,off,64);sl+=__shfl_xor(sl,off,64);
            sc+=__shfl_xor(sc,off,64);kk+=__shfl_xor(kk,off,64);st+=__shfl_xor(st,off,64);
        }
        if (tid==0){
            float loss_l=(np>0.f)?sl/(4.f*np):0.f;
            float lcp=(np>0.f)?sc/np:0.f;
            float lcn=(kk>0.f)?st/kk:0.f;
            out[0]=loss_l;out[1]=lcp+lcn;out[2]=lcp;out[3]=lcn;
        }
    }
}

extern "C" void kernel_launch(void* const* d_in, const int* in_sizes, int n_in,
                              void* d_out, int out_size, void* d_ws, size_t ws_size,
                              hipStream_t stream) {
    const float* loc     = (const float*)d_in[0];
    const float* conf    = (const float*)d_in[1];
    const float* dboxp   = (const float*)d_in[2];
    const float* targets = (const float*)d_in[3];
    float* out = (float*)d_out;

    k1<<<NB*NSPLIT, BLK1, 0, stream>>>(loc, conf, dboxp, targets);
    k2<<<NB, BLK2, 0, stream>>>(loc, conf, dboxp, targets, out);
}